// Round 1
// baseline (326743.091 us; speedup 1.0000x reference)
//
#include <hip/hip_runtime.h>
#include <hip/hip_cooperative_groups.h>
#include <math.h>

namespace cg = cooperative_groups;

#define T_   2048
#define N_   128
#define NS_  64
#define NA_  8
#define NFC_ 128
#define NH_  128
// derived
#define DX_  192   // (NN+1)*NS
#define DP_  16    // NN*NA
#define DM_  256   // NN*NH
#define G3_  384   // 3*NFC
#define G4_  512   // 4*NH

struct Params {
  const float* obs; const float* fps; const float* dones; const float* states0;
  const float* W_fcx; const float* b_fcx;
  const float* W_fcp; const float* b_fcp;
  const float* W_fcm; const float* b_fcm;
  const float* W_gat; const float* a_src; const float* a_dst;
  const float* W_ih;  const float* W_hh;  const float* b_lstm;
  const float* W_act; const float* b_act;
  const float* W_cri; const float* b_cri;
  const int* acts; const int* nbr;
  float* out;
  float* h_buf;    // N * NH
  float* Wh_buf;   // N * G3
  float* dst_buf;  // N
};

__device__ __forceinline__ float sigm(float x) { return 1.f / (1.f + expf(-x)); }

__global__ void __launch_bounds__(512) policy_scan_kernel(Params p) {
  cg::grid_group grid = cg::this_grid();
  const int tid = threadIdx.x;
  const int n   = blockIdx.x;
  const int nb0 = p.nbr[n * 2 + 0];
  const int nb1 = p.nbr[n * 2 + 1];

  __shared__ float sh_h[NH_];
  __shared__ float sh_c[NH_];
  __shared__ float sh_xin[DX_];
  __shared__ float sh_pin[DP_];
  __shared__ float sh_min[DM_];
  __shared__ float sh_feat[G3_];
  __shared__ float sh_Wh[G3_];
  __shared__ float sh_sgat[G3_];
  __shared__ float sh_gates[G4_];
  __shared__ float sh_src;

  // ---- init: load h0/c0, publish h0 ----
  if (tid < NH_) {
    float h0 = p.states0[n * (2 * NH_) + tid];
    float c0 = p.states0[n * (2 * NH_) + NH_ + tid];
    sh_h[tid] = h0;
    sh_c[tid] = c0;
    p.h_buf[n * NH_ + tid] = h0;
  }
  __threadfence();
  grid.sync();

  for (int t = 0; t < T_; ++t) {
    const float keep  = 1.f - p.dones[(size_t)t * N_ + n];
    const float keep0 = 1.f - p.dones[(size_t)t * N_ + nb0];
    const float keep1 = 1.f - p.dones[(size_t)t * N_ + nb1];

    // mask carried state (reference: state *= (1-done) at step start)
    if (tid < NH_) { sh_h[tid] *= keep; sh_c[tid] *= keep; }

    // ---- stage-1 input staging ----
    if (tid < DX_) {
      int k = tid >> 6, d = tid & 63;
      int agent = (k == 0) ? n : ((k == 1) ? nb0 : nb1);
      sh_xin[tid] = p.obs[((size_t)t * N_ + agent) * NS_ + d];
    }
    {
      int u = tid - DX_;              // [0,16): fps of neighbors
      if (u >= 0 && u < DP_) {
        int k = u >> 3, a = u & 7;
        int agent = (k == 0) ? nb0 : nb1;
        sh_pin[u] = p.fps[((size_t)t * N_ + agent) * NA_ + a];
      }
      int v = tid - (DX_ + DP_);      // [0,256): masked neighbor h
      if (v >= 0 && v < DM_) {
        int k = v >> 7, f = v & 127;
        int agent = (k == 0) ? nb0 : nb1;
        float kp  = (k == 0) ? keep0 : keep1;
        sh_min[v] = p.h_buf[agent * NH_ + f] * kp;
      }
    }
    __syncthreads();

    // ---- stage-1 FCs: s_feat = [x | p | m] ----
    if (tid < NFC_) {                       // x: 192-dot
      const float* w = p.W_fcx + ((size_t)n * DX_) * NFC_ + tid;
      float acc = p.b_fcx[n * NFC_ + tid];
      #pragma unroll 4
      for (int d = 0; d < DX_; ++d) acc = fmaf(sh_xin[d], w[(size_t)d * NFC_], acc);
      sh_feat[tid] = fmaxf(acc, 0.f);
    } else if (tid < 2 * NFC_) {            // p: 16-dot
      int f = tid - NFC_;
      const float* w = p.W_fcp + ((size_t)n * DP_) * NFC_ + f;
      float acc = p.b_fcp[n * NFC_ + f];
      #pragma unroll
      for (int d = 0; d < DP_; ++d) acc = fmaf(sh_pin[d], w[(size_t)d * NFC_], acc);
      sh_feat[NFC_ + f] = fmaxf(acc, 0.f);
    } else if (tid < 3 * NFC_) {            // m: 256-dot
      int f = tid - 2 * NFC_;
      const float* w = p.W_fcm + ((size_t)n * DM_) * NFC_ + f;
      float acc = p.b_fcm[n * NFC_ + f];
      #pragma unroll 4
      for (int d = 0; d < DM_; ++d) acc = fmaf(sh_min[d], w[(size_t)d * NFC_], acc);
      sh_feat[2 * NFC_ + f] = fmaxf(acc, 0.f);
    }
    __syncthreads();

    // ---- Wh = s_feat @ W_gat ----
    if (tid < G3_) {
      const float* w = p.W_gat + tid;
      float acc = 0.f;
      #pragma unroll 4
      for (int d = 0; d < G3_; ++d) acc = fmaf(sh_feat[d], w[(size_t)d * G3_], acc);
      sh_Wh[tid] = acc;
      p.Wh_buf[n * G3_ + tid] = acc;
    }
    __syncthreads();

    // ---- src/dst scalars (two waves reduce) ----
    if (tid < 64) {
      float s = 0.f;
      for (int g = tid; g < G3_; g += 64) s += sh_Wh[g] * p.a_src[g];
      for (int off = 32; off; off >>= 1) s += __shfl_down(s, off);
      if (tid == 0) sh_src = s;
    } else if (tid < 128) {
      int l = tid - 64;
      float s = 0.f;
      for (int g = l; g < G3_; g += 64) s += sh_Wh[g] * p.a_dst[g];
      for (int off = 32; off; off >>= 1) s += __shfl_down(s, off);
      if (l == 0) p.dst_buf[n] = s;
    }
    __threadfence();
    grid.sync();   // Wh_buf / dst_buf published

    // ---- GAT attention over ring {nb0, n, nb1} (redundant per thread) ----
    const float src_n = sh_src;
    float e_l = src_n + p.dst_buf[nb0];
    float e_s = src_n + p.dst_buf[n];
    float e_r = src_n + p.dst_buf[nb1];
    e_l = (e_l >= 0.f) ? e_l : 0.2f * e_l;
    e_s = (e_s >= 0.f) ? e_s : 0.2f * e_s;
    e_r = (e_r >= 0.f) ? e_r : 0.2f * e_r;
    float mx = fmaxf(e_l, fmaxf(e_s, e_r));
    float wl = expf(e_l - mx), wsf = expf(e_s - mx), wr = expf(e_r - mx);
    float inv = 1.f / (wl + wsf + wr);
    wl *= inv; wsf *= inv; wr *= inv;

    if (tid < G3_) {
      float v = wsf * sh_Wh[tid]
              + wl  * p.Wh_buf[nb0 * G3_ + tid]
              + wr  * p.Wh_buf[nb1 * G3_ + tid];
      sh_sgat[tid] = (v > 0.f) ? v : expm1f(v);   // elu
    }
    __syncthreads();

    // ---- LSTM gates ----
    {
      const int g = tid;
      const float* wih = p.W_ih + ((size_t)n * G3_) * G4_ + g;
      const float* whh = p.W_hh + ((size_t)n * NH_) * G4_ + g;
      float acc = p.b_lstm[n * G4_ + g];
      #pragma unroll 4
      for (int d = 0; d < G3_; ++d) acc = fmaf(sh_sgat[d], wih[(size_t)d * G4_], acc);
      #pragma unroll 4
      for (int d = 0; d < NH_; ++d) acc = fmaf(sh_h[d], whh[(size_t)d * G4_], acc);
      sh_gates[g] = acc;
    }
    __syncthreads();

    // ---- LSTM update ----
    if (tid < NH_) {
      float gi = sh_gates[tid];
      float gf = sh_gates[NH_ + tid];
      float gg = sh_gates[2 * NH_ + tid];
      float go = sh_gates[3 * NH_ + tid];
      float c_new = sigm(gf) * sh_c[tid] + sigm(gi) * tanhf(gg);
      float h_new = sigm(go) * tanhf(c_new);
      sh_c[tid] = c_new;
      sh_h[tid] = h_new;
      p.h_buf[n * NH_ + tid] = h_new;
    }
    __syncthreads();

    // ---- heads (fused; avoid storing hs) ----
    if (tid < NA_) {
      const float* wa = p.W_act + ((size_t)n * NH_) * NA_ + tid;
      float acc = p.b_act[n * NA_ + tid];
      #pragma unroll 4
      for (int d = 0; d < NH_; ++d) acc = fmaf(sh_h[d], wa[(size_t)d * NA_], acc);
      p.out[((size_t)t * N_ + n) * 9 + tid] = acc;
    } else if (tid == NA_) {
      const float* wc = p.W_cri + (size_t)n * 144;
      float acc = p.b_cri[n];
      #pragma unroll 4
      for (int d = 0; d < NH_; ++d) acc = fmaf(sh_h[d], wc[d], acc);
      acc += wc[NH_ + p.acts[(size_t)t * N_ + nb0]];
      acc += wc[NH_ + NA_ + p.acts[(size_t)t * N_ + nb1]];
      p.out[((size_t)t * N_ + n) * 9 + 8] = acc;
    }
    __threadfence();
    grid.sync();   // h_buf published for step t+1
  }
}

extern "C" void kernel_launch(void* const* d_in, const int* in_sizes, int n_in,
                              void* d_out, int out_size, void* d_ws, size_t ws_size,
                              hipStream_t stream) {
  Params p;
  p.obs     = (const float*)d_in[0];
  p.fps     = (const float*)d_in[1];
  p.dones   = (const float*)d_in[2];
  p.states0 = (const float*)d_in[3];
  p.W_fcx   = (const float*)d_in[4];
  p.b_fcx   = (const float*)d_in[5];
  p.W_fcp   = (const float*)d_in[6];
  p.b_fcp   = (const float*)d_in[7];
  p.W_fcm   = (const float*)d_in[8];
  p.b_fcm   = (const float*)d_in[9];
  p.W_gat   = (const float*)d_in[10];
  p.a_src   = (const float*)d_in[11];
  p.a_dst   = (const float*)d_in[12];
  p.W_ih    = (const float*)d_in[13];
  p.W_hh    = (const float*)d_in[14];
  p.b_lstm  = (const float*)d_in[15];
  p.W_act   = (const float*)d_in[16];
  p.b_act   = (const float*)d_in[17];
  p.W_cri   = (const float*)d_in[18];
  p.b_cri   = (const float*)d_in[19];
  p.acts    = (const int*)d_in[20];
  p.nbr     = (const int*)d_in[21];
  // d_in[22] = adj — ring structure implied by nbr; not needed.
  p.out     = (float*)d_out;

  float* ws = (float*)d_ws;
  p.h_buf   = ws;                         // N*NH      = 16384 floats
  p.Wh_buf  = ws + N_ * NH_;              // N*G3      = 49152 floats
  p.dst_buf = ws + N_ * NH_ + N_ * G3_;   // N         = 128 floats

  void* args[] = { &p };
  hipLaunchCooperativeKernel((const void*)policy_scan_kernel,
                             dim3(N_), dim3(512), args, 0, stream);
}

// Round 2
// 215953.857 us; speedup vs baseline: 1.5130x; 1.5130x over previous
//
#include <hip/hip_runtime.h>
#include <hip/hip_cooperative_groups.h>
#include <hip/hip_bf16.h>
#include <math.h>

namespace cg = cooperative_groups;

#define T_   2048
#define N_   128
#define NS_  64
#define NA_  8
#define NFC_ 128
#define NH_  128
// derived
#define DX_  192   // (NN+1)*NS
#define DP_  16    // NN*NA
#define DM_  256   // NN*NH
#define G3_  384   // 3*NFC
#define G4_  512   // 4*NH

// ---------------- bf16 transposed-row dot helpers ----------------
// w: row of NW*8 bf16 (contiguous, 16B aligned). x: fp32 LDS array (16B aligned).
// 4 accumulators to break FMA dependency chain; full unroll -> deep MLP.
template<int NW>
__device__ __forceinline__ float dot_bf16T(const __hip_bfloat16* __restrict__ w,
                                           const float* __restrict__ x) {
  const uint4* wv = reinterpret_cast<const uint4*>(w);
  const float4* xv = reinterpret_cast<const float4*>(x);
  float a0 = 0.f, a1 = 0.f, a2 = 0.f, a3 = 0.f;
  #pragma unroll
  for (int i = 0; i < NW; ++i) {
    uint4 u = wv[i];
    float4 x0 = xv[2 * i];
    float4 x1 = xv[2 * i + 1];
    a0 = fmaf(__uint_as_float(u.x << 16),          x0.x, a0);
    a1 = fmaf(__uint_as_float(u.x & 0xffff0000u),  x0.y, a1);
    a2 = fmaf(__uint_as_float(u.y << 16),          x0.z, a2);
    a3 = fmaf(__uint_as_float(u.y & 0xffff0000u),  x0.w, a3);
    a0 = fmaf(__uint_as_float(u.z << 16),          x1.x, a0);
    a1 = fmaf(__uint_as_float(u.z & 0xffff0000u),  x1.y, a1);
    a2 = fmaf(__uint_as_float(u.w << 16),          x1.z, a2);
    a3 = fmaf(__uint_as_float(u.w & 0xffff0000u),  x1.w, a3);
  }
  return (a0 + a1) + (a2 + a3);
}

struct Params {
  const float* obs; const float* fps; const float* dones; const float* states0;
  const float* b_fcx; const float* b_fcp; const float* b_fcm;
  const float* a_src; const float* a_dst;
  const float* b_lstm; const float* b_act;
  const float* W_cri; const float* b_cri;
  const int* acts; const int* nbr;
  float* out;
  // workspace
  float* h_buf;    // N*NH
  float* Wh_buf;   // N*G3
  float* dst_buf;  // N
  const __hip_bfloat16* ihT;   // [N][G4][G3]
  const __hip_bfloat16* hhT;   // [N][G4][NH]
  const __hip_bfloat16* gatT;  // [G3][G3]
  const __hip_bfloat16* fcxT;  // [N][NFC][DX]
  const __hip_bfloat16* fcpT;  // [N][NFC][DP]
  const __hip_bfloat16* fcmT;  // [N][NFC][DM]
  const __hip_bfloat16* actT;  // [N][NA][NH]
};

__device__ __forceinline__ float sigm(float x) { return 1.f / (1.f + expf(-x)); }

// ---------------- prep: transpose [A][D][G] fp32 -> [A][G][D] bf16 ----------------
__global__ void transpose_to_bf16(const float* __restrict__ src, __hip_bfloat16* __restrict__ dst,
                                  int A, int D, int G) {
  size_t total = (size_t)A * D * G;
  size_t stride = (size_t)gridDim.x * blockDim.x;
  for (size_t i = (size_t)blockIdx.x * blockDim.x + threadIdx.x; i < total; i += stride) {
    size_t dg = (size_t)D * G;
    size_t a = i / dg;
    size_t r = i - a * dg;
    size_t g = r / D, d = r - g * D;
    dst[i] = __float2bfloat16(src[a * dg + d * G + g]);
  }
}

// ---------------- main persistent scan kernel (bf16 weights) ----------------
__global__ void __launch_bounds__(512) policy_scan_bf16(Params p) {
  cg::grid_group grid = cg::this_grid();
  const int tid = threadIdx.x;
  const int n   = blockIdx.x;
  const int nb0 = p.nbr[n * 2 + 0];
  const int nb1 = p.nbr[n * 2 + 1];

  __shared__ __align__(16) float sh_h[NH_];
  __shared__ __align__(16) float sh_c[NH_];
  __shared__ __align__(16) float sh_xin[DX_];
  __shared__ __align__(16) float sh_pin[DP_];
  __shared__ __align__(16) float sh_min[DM_];
  __shared__ __align__(16) float sh_feat[G3_];
  __shared__ __align__(16) float sh_Wh[G3_];
  __shared__ __align__(16) float sh_sgat[G3_];
  __shared__ __align__(16) float sh_gates[G4_];
  __shared__ float sh_src;

  if (tid < NH_) {
    float h0 = p.states0[n * (2 * NH_) + tid];
    float c0 = p.states0[n * (2 * NH_) + NH_ + tid];
    sh_h[tid] = h0;
    sh_c[tid] = c0;
    p.h_buf[n * NH_ + tid] = h0;
  }
  __threadfence();
  grid.sync();

  for (int t = 0; t < T_; ++t) {
    const float keep  = 1.f - p.dones[(size_t)t * N_ + n];
    const float keep0 = 1.f - p.dones[(size_t)t * N_ + nb0];
    const float keep1 = 1.f - p.dones[(size_t)t * N_ + nb1];

    if (tid < NH_) { sh_h[tid] *= keep; sh_c[tid] *= keep; }

    // ---- input staging ----
    if (tid < DX_) {
      int k = tid >> 6, d = tid & 63;
      int agent = (k == 0) ? n : ((k == 1) ? nb0 : nb1);
      sh_xin[tid] = p.obs[((size_t)t * N_ + agent) * NS_ + d];
    }
    {
      int u = tid - DX_;
      if (u >= 0 && u < DP_) {
        int k = u >> 3, a = u & 7;
        int agent = (k == 0) ? nb0 : nb1;
        sh_pin[u] = p.fps[((size_t)t * N_ + agent) * NA_ + a];
      }
      int v = tid - (DX_ + DP_);
      if (v >= 0 && v < DM_) {
        int k = v >> 7, f = v & 127;
        int agent = (k == 0) ? nb0 : nb1;
        float kp  = (k == 0) ? keep0 : keep1;
        sh_min[v] = p.h_buf[agent * NH_ + f] * kp;
      }
    }
    __syncthreads();

    // ---- stage-1 FCs ----
    if (tid < NFC_) {
      float acc = p.b_fcx[n * NFC_ + tid]
                + dot_bf16T<DX_ / 8>(p.fcxT + ((size_t)n * NFC_ + tid) * DX_, sh_xin);
      sh_feat[tid] = fmaxf(acc, 0.f);
    } else if (tid < 2 * NFC_) {
      int f = tid - NFC_;
      float acc = p.b_fcp[n * NFC_ + f]
                + dot_bf16T<DP_ / 8>(p.fcpT + ((size_t)n * NFC_ + f) * DP_, sh_pin);
      sh_feat[NFC_ + f] = fmaxf(acc, 0.f);
    } else if (tid < 3 * NFC_) {
      int f = tid - 2 * NFC_;
      float acc = p.b_fcm[n * NFC_ + f]
                + dot_bf16T<DM_ / 8>(p.fcmT + ((size_t)n * NFC_ + f) * DM_, sh_min);
      sh_feat[2 * NFC_ + f] = fmaxf(acc, 0.f);
    }
    __syncthreads();

    // ---- Wh = s_feat @ W_gat (gatT shared across agents -> L2-hot) ----
    if (tid < G3_) {
      float acc = dot_bf16T<G3_ / 8>(p.gatT + (size_t)tid * G3_, sh_feat);
      sh_Wh[tid] = acc;
      p.Wh_buf[n * G3_ + tid] = acc;
    }
    __syncthreads();

    // ---- src/dst scalars ----
    if (tid < 64) {
      float s = 0.f;
      for (int g = tid; g < G3_; g += 64) s += sh_Wh[g] * p.a_src[g];
      for (int off = 32; off; off >>= 1) s += __shfl_down(s, off);
      if (tid == 0) sh_src = s;
    } else if (tid < 128) {
      int l = tid - 64;
      float s = 0.f;
      for (int g = l; g < G3_; g += 64) s += sh_Wh[g] * p.a_dst[g];
      for (int off = 32; off; off >>= 1) s += __shfl_down(s, off);
      if (l == 0) p.dst_buf[n] = s;
    }
    __threadfence();
    grid.sync();   // Wh_buf / dst_buf published

    // ---- GAT ring attention ----
    const float src_n = sh_src;
    float e_l = src_n + p.dst_buf[nb0];
    float e_s = src_n + p.dst_buf[n];
    float e_r = src_n + p.dst_buf[nb1];
    e_l = (e_l >= 0.f) ? e_l : 0.2f * e_l;
    e_s = (e_s >= 0.f) ? e_s : 0.2f * e_s;
    e_r = (e_r >= 0.f) ? e_r : 0.2f * e_r;
    float mx = fmaxf(e_l, fmaxf(e_s, e_r));
    float wl = expf(e_l - mx), wsf = expf(e_s - mx), wr = expf(e_r - mx);
    float inv = 1.f / (wl + wsf + wr);
    wl *= inv; wsf *= inv; wr *= inv;

    if (tid < G3_) {
      float v = wsf * sh_Wh[tid]
              + wl  * p.Wh_buf[nb0 * G3_ + tid]
              + wr  * p.Wh_buf[nb1 * G3_ + tid];
      sh_sgat[tid] = (v > 0.f) ? v : expm1f(v);
    }
    __syncthreads();

    // ---- LSTM gates: every thread owns one g ----
    {
      const int g = tid;
      float acc = p.b_lstm[n * G4_ + g];
      acc += dot_bf16T<G3_ / 8>(p.ihT + ((size_t)n * G4_ + g) * G3_, sh_sgat);
      acc += dot_bf16T<NH_ / 8>(p.hhT + ((size_t)n * G4_ + g) * NH_, sh_h);
      sh_gates[g] = acc;
    }
    __syncthreads();

    // ---- LSTM state update ----
    if (tid < NH_) {
      float gi = sh_gates[tid];
      float gf = sh_gates[NH_ + tid];
      float gg = sh_gates[2 * NH_ + tid];
      float go = sh_gates[3 * NH_ + tid];
      float c_new = sigm(gf) * sh_c[tid] + sigm(gi) * tanhf(gg);
      float h_new = sigm(go) * tanhf(c_new);
      sh_c[tid] = c_new;
      sh_h[tid] = h_new;
      p.h_buf[n * NH_ + tid] = h_new;
    }
    __syncthreads();

    // ---- heads ----
    if (tid >= 384 && tid < 448) {
      // actor: 8 outputs x 8 lanes each (2 uint4 per lane over NH=128)
      int l = tid - 384;
      int a = l >> 3, k = l & 7;
      const uint4* wv = reinterpret_cast<const uint4*>(p.actT + ((size_t)n * NA_ + a) * NH_);
      const float4* xv = reinterpret_cast<const float4*>(sh_h);
      float pp = 0.f;
      #pragma unroll
      for (int i = 0; i < 2; ++i) {
        uint4 u = wv[k * 2 + i];
        float4 x0 = xv[(k * 2 + i) * 2];
        float4 x1 = xv[(k * 2 + i) * 2 + 1];
        pp = fmaf(__uint_as_float(u.x << 16),         x0.x, pp);
        pp = fmaf(__uint_as_float(u.x & 0xffff0000u), x0.y, pp);
        pp = fmaf(__uint_as_float(u.y << 16),         x0.z, pp);
        pp = fmaf(__uint_as_float(u.y & 0xffff0000u), x0.w, pp);
        pp = fmaf(__uint_as_float(u.z << 16),         x1.x, pp);
        pp = fmaf(__uint_as_float(u.z & 0xffff0000u), x1.y, pp);
        pp = fmaf(__uint_as_float(u.w << 16),         x1.z, pp);
        pp = fmaf(__uint_as_float(u.w & 0xffff0000u), x1.w, pp);
      }
      pp += __shfl_down(pp, 4, 8);
      pp += __shfl_down(pp, 2, 8);
      pp += __shfl_down(pp, 1, 8);
      if (k == 0) p.out[((size_t)t * N_ + n) * 9 + a] = pp + p.b_act[n * NA_ + a];
    } else if (tid >= 448) {
      // critic: 64-lane reduction over h
      int l = tid - 448;
      const float* wc = p.W_cri + (size_t)n * 144;
      float pp = sh_h[l] * wc[l] + sh_h[64 + l] * wc[64 + l];
      for (int off = 32; off; off >>= 1) pp += __shfl_down(pp, off);
      if (l == 0) {
        pp += p.b_cri[n];
        pp += wc[NH_ + p.acts[(size_t)t * N_ + nb0]];
        pp += wc[NH_ + NA_ + p.acts[(size_t)t * N_ + nb1]];
        p.out[((size_t)t * N_ + n) * 9 + 8] = pp;
      }
    }
    __threadfence();
    grid.sync();   // h_buf published for step t+1
  }
}

// ---------------- fallback: round-0 fp32 kernel (used if ws too small) ----------------
struct ParamsF {
  const float* obs; const float* fps; const float* dones; const float* states0;
  const float* W_fcx; const float* b_fcx;
  const float* W_fcp; const float* b_fcp;
  const float* W_fcm; const float* b_fcm;
  const float* W_gat; const float* a_src; const float* a_dst;
  const float* W_ih;  const float* W_hh;  const float* b_lstm;
  const float* W_act; const float* b_act;
  const float* W_cri; const float* b_cri;
  const int* acts; const int* nbr;
  float* out; float* h_buf; float* Wh_buf; float* dst_buf;
};

__global__ void __launch_bounds__(512) policy_scan_f32(ParamsF p) {
  cg::grid_group grid = cg::this_grid();
  const int tid = threadIdx.x;
  const int n   = blockIdx.x;
  const int nb0 = p.nbr[n * 2 + 0];
  const int nb1 = p.nbr[n * 2 + 1];
  __shared__ float sh_h[NH_], sh_c[NH_], sh_xin[DX_], sh_pin[DP_], sh_min[DM_];
  __shared__ float sh_feat[G3_], sh_Wh[G3_], sh_sgat[G3_], sh_gates[G4_], sh_src;
  if (tid < NH_) {
    float h0 = p.states0[n * (2 * NH_) + tid];
    float c0 = p.states0[n * (2 * NH_) + NH_ + tid];
    sh_h[tid] = h0; sh_c[tid] = c0; p.h_buf[n * NH_ + tid] = h0;
  }
  __threadfence();
  grid.sync();
  for (int t = 0; t < T_; ++t) {
    const float keep  = 1.f - p.dones[(size_t)t * N_ + n];
    const float keep0 = 1.f - p.dones[(size_t)t * N_ + nb0];
    const float keep1 = 1.f - p.dones[(size_t)t * N_ + nb1];
    if (tid < NH_) { sh_h[tid] *= keep; sh_c[tid] *= keep; }
    if (tid < DX_) {
      int k = tid >> 6, d = tid & 63;
      int agent = (k == 0) ? n : ((k == 1) ? nb0 : nb1);
      sh_xin[tid] = p.obs[((size_t)t * N_ + agent) * NS_ + d];
    }
    {
      int u = tid - DX_;
      if (u >= 0 && u < DP_) {
        int k = u >> 3, a = u & 7;
        sh_pin[u] = p.fps[((size_t)t * N_ + ((k == 0) ? nb0 : nb1)) * NA_ + a];
      }
      int v = tid - (DX_ + DP_);
      if (v >= 0 && v < DM_) {
        int k = v >> 7, f = v & 127;
        sh_min[v] = p.h_buf[((k == 0) ? nb0 : nb1) * NH_ + f] * ((k == 0) ? keep0 : keep1);
      }
    }
    __syncthreads();
    if (tid < NFC_) {
      const float* w = p.W_fcx + ((size_t)n * DX_) * NFC_ + tid;
      float acc = p.b_fcx[n * NFC_ + tid];
      #pragma unroll 4
      for (int d = 0; d < DX_; ++d) acc = fmaf(sh_xin[d], w[(size_t)d * NFC_], acc);
      sh_feat[tid] = fmaxf(acc, 0.f);
    } else if (tid < 2 * NFC_) {
      int f = tid - NFC_;
      const float* w = p.W_fcp + ((size_t)n * DP_) * NFC_ + f;
      float acc = p.b_fcp[n * NFC_ + f];
      #pragma unroll
      for (int d = 0; d < DP_; ++d) acc = fmaf(sh_pin[d], w[(size_t)d * NFC_], acc);
      sh_feat[NFC_ + f] = fmaxf(acc, 0.f);
    } else if (tid < 3 * NFC_) {
      int f = tid - 2 * NFC_;
      const float* w = p.W_fcm + ((size_t)n * DM_) * NFC_ + f;
      float acc = p.b_fcm[n * NFC_ + f];
      #pragma unroll 4
      for (int d = 0; d < DM_; ++d) acc = fmaf(sh_min[d], w[(size_t)d * NFC_], acc);
      sh_feat[2 * NFC_ + f] = fmaxf(acc, 0.f);
    }
    __syncthreads();
    if (tid < G3_) {
      const float* w = p.W_gat + tid;
      float acc = 0.f;
      #pragma unroll 4
      for (int d = 0; d < G3_; ++d) acc = fmaf(sh_feat[d], w[(size_t)d * G3_], acc);
      sh_Wh[tid] = acc;
      p.Wh_buf[n * G3_ + tid] = acc;
    }
    __syncthreads();
    if (tid < 64) {
      float s = 0.f;
      for (int g = tid; g < G3_; g += 64) s += sh_Wh[g] * p.a_src[g];
      for (int off = 32; off; off >>= 1) s += __shfl_down(s, off);
      if (tid == 0) sh_src = s;
    } else if (tid < 128) {
      int l = tid - 64;
      float s = 0.f;
      for (int g = l; g < G3_; g += 64) s += sh_Wh[g] * p.a_dst[g];
      for (int off = 32; off; off >>= 1) s += __shfl_down(s, off);
      if (l == 0) p.dst_buf[n] = s;
    }
    __threadfence();
    grid.sync();
    const float src_n = sh_src;
    float e_l = src_n + p.dst_buf[nb0];
    float e_s = src_n + p.dst_buf[n];
    float e_r = src_n + p.dst_buf[nb1];
    e_l = (e_l >= 0.f) ? e_l : 0.2f * e_l;
    e_s = (e_s >= 0.f) ? e_s : 0.2f * e_s;
    e_r = (e_r >= 0.f) ? e_r : 0.2f * e_r;
    float mx = fmaxf(e_l, fmaxf(e_s, e_r));
    float wl = expf(e_l - mx), wsf = expf(e_s - mx), wr = expf(e_r - mx);
    float inv = 1.f / (wl + wsf + wr);
    wl *= inv; wsf *= inv; wr *= inv;
    if (tid < G3_) {
      float v = wsf * sh_Wh[tid] + wl * p.Wh_buf[nb0 * G3_ + tid] + wr * p.Wh_buf[nb1 * G3_ + tid];
      sh_sgat[tid] = (v > 0.f) ? v : expm1f(v);
    }
    __syncthreads();
    {
      const int g = tid;
      const float* wih = p.W_ih + ((size_t)n * G3_) * G4_ + g;
      const float* whh = p.W_hh + ((size_t)n * NH_) * G4_ + g;
      float acc = p.b_lstm[n * G4_ + g];
      #pragma unroll 4
      for (int d = 0; d < G3_; ++d) acc = fmaf(sh_sgat[d], wih[(size_t)d * G4_], acc);
      #pragma unroll 4
      for (int d = 0; d < NH_; ++d) acc = fmaf(sh_h[d], whh[(size_t)d * G4_], acc);
      sh_gates[g] = acc;
    }
    __syncthreads();
    if (tid < NH_) {
      float gi = sh_gates[tid], gf = sh_gates[NH_ + tid];
      float gg = sh_gates[2 * NH_ + tid], go = sh_gates[3 * NH_ + tid];
      float c_new = sigm(gf) * sh_c[tid] + sigm(gi) * tanhf(gg);
      float h_new = sigm(go) * tanhf(c_new);
      sh_c[tid] = c_new; sh_h[tid] = h_new;
      p.h_buf[n * NH_ + tid] = h_new;
    }
    __syncthreads();
    if (tid < NA_) {
      const float* wa = p.W_act + ((size_t)n * NH_) * NA_ + tid;
      float acc = p.b_act[n * NA_ + tid];
      #pragma unroll 4
      for (int d = 0; d < NH_; ++d) acc = fmaf(sh_h[d], wa[(size_t)d * NA_], acc);
      p.out[((size_t)t * N_ + n) * 9 + tid] = acc;
    } else if (tid == NA_) {
      const float* wc = p.W_cri + (size_t)n * 144;
      float acc = p.b_cri[n];
      #pragma unroll 4
      for (int d = 0; d < NH_; ++d) acc = fmaf(sh_h[d], wc[d], acc);
      acc += wc[NH_ + p.acts[(size_t)t * N_ + nb0]];
      acc += wc[NH_ + NA_ + p.acts[(size_t)t * N_ + nb1]];
      p.out[((size_t)t * N_ + n) * 9 + 8] = acc;
    }
    __threadfence();
    grid.sync();
  }
}

extern "C" void kernel_launch(void* const* d_in, const int* in_sizes, int n_in,
                              void* d_out, int out_size, void* d_ws, size_t ws_size,
                              hipStream_t stream) {
  const float* obs    = (const float*)d_in[0];
  const float* fps    = (const float*)d_in[1];
  const float* dones  = (const float*)d_in[2];
  const float* states0= (const float*)d_in[3];
  const float* W_fcx  = (const float*)d_in[4];
  const float* b_fcx  = (const float*)d_in[5];
  const float* W_fcp  = (const float*)d_in[6];
  const float* b_fcp  = (const float*)d_in[7];
  const float* W_fcm  = (const float*)d_in[8];
  const float* b_fcm  = (const float*)d_in[9];
  const float* W_gat  = (const float*)d_in[10];
  const float* a_src  = (const float*)d_in[11];
  const float* a_dst  = (const float*)d_in[12];
  const float* W_ih   = (const float*)d_in[13];
  const float* W_hh   = (const float*)d_in[14];
  const float* b_lstm = (const float*)d_in[15];
  const float* W_act  = (const float*)d_in[16];
  const float* b_act  = (const float*)d_in[17];
  const float* W_cri  = (const float*)d_in[18];
  const float* b_cri  = (const float*)d_in[19];
  const int*   acts   = (const int*)d_in[20];
  const int*   nbr    = (const int*)d_in[21];

  // workspace layout
  char* ws = (char*)d_ws;
  size_t off = 0;
  float* h_buf   = (float*)(ws + off); off += (size_t)N_ * NH_ * 4;          // 65,536
  float* Wh_buf  = (float*)(ws + off); off += (size_t)N_ * G3_ * 4;          // 196,608
  float* dst_buf = (float*)(ws + off); off += 512;                           // 128 f + pad
  __hip_bfloat16* ihT  = (__hip_bfloat16*)(ws + off); off += (size_t)N_ * G4_ * G3_ * 2;
  __hip_bfloat16* hhT  = (__hip_bfloat16*)(ws + off); off += (size_t)N_ * G4_ * NH_ * 2;
  __hip_bfloat16* gatT = (__hip_bfloat16*)(ws + off); off += (size_t)G3_ * G3_ * 2;
  __hip_bfloat16* fcxT = (__hip_bfloat16*)(ws + off); off += (size_t)N_ * NFC_ * DX_ * 2;
  __hip_bfloat16* fcpT = (__hip_bfloat16*)(ws + off); off += (size_t)N_ * NFC_ * DP_ * 2;
  __hip_bfloat16* fcmT = (__hip_bfloat16*)(ws + off); off += (size_t)N_ * NFC_ * DM_ * 2;
  __hip_bfloat16* actT = (__hip_bfloat16*)(ws + off); off += (size_t)N_ * NA_ * NH_ * 2;

  if (ws_size < off) {
    // fallback: fp32 streaming kernel (round-0, known correct)
    ParamsF p;
    p.obs = obs; p.fps = fps; p.dones = dones; p.states0 = states0;
    p.W_fcx = W_fcx; p.b_fcx = b_fcx; p.W_fcp = W_fcp; p.b_fcp = b_fcp;
    p.W_fcm = W_fcm; p.b_fcm = b_fcm; p.W_gat = W_gat; p.a_src = a_src; p.a_dst = a_dst;
    p.W_ih = W_ih; p.W_hh = W_hh; p.b_lstm = b_lstm;
    p.W_act = W_act; p.b_act = b_act; p.W_cri = W_cri; p.b_cri = b_cri;
    p.acts = acts; p.nbr = nbr; p.out = (float*)d_out;
    p.h_buf = h_buf; p.Wh_buf = Wh_buf; p.dst_buf = dst_buf;
    void* args[] = { &p };
    hipLaunchCooperativeKernel((const void*)policy_scan_f32, dim3(N_), dim3(512), args, 0, stream);
    return;
  }

  // prep: transpose+convert weights to bf16 [out][in] rows
  {
    dim3 blk(256);
    transpose_to_bf16<<<dim3(4096), blk, 0, stream>>>(W_ih,  ihT,  N_, G3_, G4_);
    transpose_to_bf16<<<dim3(2048), blk, 0, stream>>>(W_hh,  hhT,  N_, NH_, G4_);
    transpose_to_bf16<<<dim3(256),  blk, 0, stream>>>(W_gat, gatT, 1,  G3_, G3_);
    transpose_to_bf16<<<dim3(1024), blk, 0, stream>>>(W_fcx, fcxT, N_, DX_, NFC_);
    transpose_to_bf16<<<dim3(256),  blk, 0, stream>>>(W_fcp, fcpT, N_, DP_, NFC_);
    transpose_to_bf16<<<dim3(1024), blk, 0, stream>>>(W_fcm, fcmT, N_, DM_, NFC_);
    transpose_to_bf16<<<dim3(128),  blk, 0, stream>>>(W_act, actT, N_, NH_, NA_);
  }

  Params p;
  p.obs = obs; p.fps = fps; p.dones = dones; p.states0 = states0;
  p.b_fcx = b_fcx; p.b_fcp = b_fcp; p.b_fcm = b_fcm;
  p.a_src = a_src; p.a_dst = a_dst;
  p.b_lstm = b_lstm; p.b_act = b_act;
  p.W_cri = W_cri; p.b_cri = b_cri;
  p.acts = acts; p.nbr = nbr;
  p.out = (float*)d_out;
  p.h_buf = h_buf; p.Wh_buf = Wh_buf; p.dst_buf = dst_buf;
  p.ihT = ihT; p.hhT = hhT; p.gatT = gatT;
  p.fcxT = fcxT; p.fcpT = fcpT; p.fcmT = fcmT; p.actT = actT;

  void* args[] = { &p };
  hipLaunchCooperativeKernel((const void*)policy_scan_bf16, dim3(N_), dim3(512), args, 0, stream);
}